// Round 2
// baseline (822.339 us; speedup 1.0000x reference)
//
#include <hip/hip_runtime.h>

#define CRF_B 256
#define CRF_S 1024
#define CRF_T 128
#define GSPLIT 8                    // gold: S-slices per batch (128 rows each)
#define WS_FWD  (CRF_B * GSPLIT)    // ws layout: [0,2048) gold partials,
#define WS_N    (WS_FWD + CRF_B)    //            [2048,2304) fwd results

typedef __attribute__((ext_vector_type(4))) float f32x4;

// Barrier that waits only on LDS ops (lgkmcnt), NOT vmcnt: keeps global
// em-prefetch loads in flight across steps (__syncthreads drains vmcnt(0)).
__device__ __forceinline__ void barrier_lds_only() {
    __asm__ volatile("s_waitcnt lgkmcnt(0)\n\ts_barrier" ::: "memory");
}

// Cross-lane butterfly adds on the VALU pipe (DPP), no LDS/bpermute (gold).
__device__ __forceinline__ float dpp_add_xor1(float x) {      // quad_perm [1,0,3,2]
    int y = __builtin_amdgcn_mov_dpp(__float_as_int(x), 0xB1, 0xF, 0xF, false);
    return x + __int_as_float(y);
}
__device__ __forceinline__ float dpp_add_xor2(float x) {      // quad_perm [2,3,0,1]
    int y = __builtin_amdgcn_mov_dpp(__float_as_int(x), 0x4E, 0xF, 0xF, false);
    return x + __int_as_float(y);
}

__device__ __forceinline__ f32x4 exp4(f32x4 v) {
    f32x4 r;
    r.x = __expf(v.x); r.y = __expf(v.y); r.z = __expf(v.z); r.w = __expf(v.w);
    return r;
}
__device__ __forceinline__ float hsum4(f32x4 v) {
    return (v.x + v.y) + (v.z + v.w);
}

// ---------------------------------------------------------------------------
// Kernel 1: tag-gather terms (negated) + S2 = sum_t m_t*log(sum_j exp(em_tj)).
// S-split across GSPLIT blocks per batch (grid 2048 -> TLP hides HBM latency).
// Per-block partial goes to ws[blockIdx.x] -- NO atomics (R1 lesson: 2048
// same-address atomicAdds serialize at L2, ~140us).
// ---------------------------------------------------------------------------
__global__ __launch_bounds__(256) void crf_gold_kernel(
    const float* __restrict__ em, const int* __restrict__ tags,
    const float* __restrict__ mask, const float* __restrict__ startT,
    const float* __restrict__ endT, const float* __restrict__ trans,
    float* __restrict__ ws)
{
    const int b     = blockIdx.x >> 3;            // GSPLIT == 8
    const int slice = blockIdx.x & (GSPLIT - 1);
    const int base  = slice << 7;                 // 128 rows per slice
    const int tid = threadIdx.x;
    const int p = tid & 3;      // quad member
    const int q = tid >> 2;     // quad id 0..63
    const int* tg = tags + (size_t)b * CRF_S;
    const float* mk = mask + (size_t)b * CRF_S;
    const float* emr = em + (size_t)b * CRF_S * CRF_T;

    // ---- tag-gather part: one t per thread (tid<128) ----
    float g_acc = 0.f;
    if (tid < 128) {
        const int t = base + tid;
        const int tagt = tg[t];
        const float m = mk[t];
        g_acc += emr[(size_t)t * CRF_T + tagt] * m;
        if (t >= 1) g_acc += trans[tg[t - 1] * CRF_T + tagt] * m;
    }
    if (tid == 0 && slice == 0)
        g_acc += startT[tg[0]];
    if (tid == 0 && slice == GSPLIT - 1)
        g_acc += endT[tg[CRF_S - 1]] * mk[CRF_S - 1];

    // ---- S2 part: quad q handles rows base+q, base+q+64; lane p cols 4p+16k
    float s2 = 0.f;
#pragma unroll
    for (int it = 0; it < 2; ++it) {
        const int r = base + it * 64 + q;
        const float* row = emr + (size_t)r * CRF_T;
        f32x4 sum4 = {0.f, 0.f, 0.f, 0.f};
#pragma unroll
        for (int k = 0; k < 8; ++k)
            sum4 += exp4(*(const f32x4*)(row + k * 16 + p * 4));
        float s = hsum4(sum4);
        s = dpp_add_xor1(s);
        s = dpp_add_xor2(s);
        if (p == 0) s2 += __logf(s) * mk[r];
    }

    float contrib = s2 - g_acc;
#pragma unroll
    for (int d = 1; d < 64; d <<= 1) contrib += __shfl_xor(contrib, d);
    __shared__ float r4[4];
    if ((tid & 63) == 0) r4[tid >> 6] = contrib;
    __syncthreads();
    if (tid == 0)
        ws[blockIdx.x] = (r4[0] + r4[1]) + (r4[2] + r4[3]);
}

// ---------------------------------------------------------------------------
// Kernel 2: scaled linear-domain forward recursion. ONE COLUMN PER LANE.
// 128 threads (2 waves), grid 256. Lane j owns output column j outright:
//   - E column j in registers: EC[k].s = exp(trans[4k+s][j]), 32 f32x4 = 128
//     VGPR (static unroll -> no scratch, fits arch-256, no AGPR moves).
//   - Per step: 32 BROADCAST ds_read_b128 of alpha (all lanes same address ->
//     HW broadcast, conflict-free), 32 f32x4 FMAs into 4 parallel accs,
//     hsum4, *eh_j, ONE ds_write_b32, lgkm-only 2-wave barrier.
//   - NO cross-lane reduce, NO leader, NO partsA: rescale csum is computed
//     redundantly per-lane during the role-3 read pass (those reads ARE
//     alpha_{t-1}, the exact values the old partsA summed). rc/logZ are
//     uniform across lanes by construction.
// This removes the old critical path's DPP tree + conflicted reads + 4-wave
// barrier; replaces with broadcast reads + 2-wave barrier.
// ---------------------------------------------------------------------------
__global__ __launch_bounds__(128, 1) void crf_fwd_kernel(
    const float* __restrict__ em, const float* __restrict__ mask,
    const float* __restrict__ startT, const float* __restrict__ endT,
    const float* __restrict__ trans, float* __restrict__ ws)
{
    const int b = blockIdx.x;
    const int j = threadIdx.x;          // owned column 0..127

    __shared__ __align__(16) float Ab[2][CRF_T];
    __shared__ float red[4];

    // E column j: EC[k].{x,y,z,w} = exp(trans[4k+s][j]); coalesced loads.
    f32x4 EC[32];
#pragma unroll
    for (int k = 0; k < 32; ++k) {
        f32x4 e;
        e.x = trans[(4 * k + 0) * CRF_T + j];
        e.y = trans[(4 * k + 1) * CRF_T + j];
        e.z = trans[(4 * k + 2) * CRF_T + j];
        e.w = trans[(4 * k + 3) * CRF_T + j];
        EC[k] = exp4(e);
    }

    const float* emb = em + (size_t)b * CRF_S * CRF_T + j;
    const float mlast = mask[(size_t)b * CRF_S + (CRF_S - 1)];

    float logZ = 0.f;   // uniform across lanes
    float rc = 1.f;     // uniform across lanes
    float aout = 0.f;   // this lane's current alpha (register copy for finale)

    // em pipeline: eh[cur] in use, eh[nxt] built this group; emv = group g+2.
    float emv[4], eh[2][4];
#pragma unroll
    for (int k = 0; k < 4; ++k) emv[k] = emb[(size_t)k * CRF_T];
#pragma unroll
    for (int k = 0; k < 4; ++k) eh[0][k] = __expf(emv[k]);
#pragma unroll
    for (int k = 0; k < 4; ++k) emv[k] = emb[(size_t)(4 + k) * CRF_T];

    auto STEP = [&](int t, int role, float ehv) {
        const int rb = (t & 1) ^ 1, wb = t & 1;
        const f32x4* A4 = (const f32x4*)&Ab[rb][0];
        const bool do_csum = (role == 3) && (t < 1023);  // role is literal ->
                                                         // branch folds away
        f32x4 acA = {0.f, 0.f, 0.f, 0.f}, acB = acA, acC = acA, acD = acA;
        f32x4 cs = acA;
#pragma unroll
        for (int k = 0; k < 32; k += 4) {
            f32x4 a0 = A4[k], a1 = A4[k + 1], a2 = A4[k + 2], a3 = A4[k + 3];
            if (do_csum) { cs += a0; cs += a1; cs += a2; cs += a3; }
            acA = __builtin_elementwise_fma(a0, EC[k],     acA);
            acB = __builtin_elementwise_fma(a1, EC[k + 1], acB);
            acC = __builtin_elementwise_fma(a2, EC[k + 2], acC);
            acD = __builtin_elementwise_fma(a3, EC[k + 3], acD);
        }
        if (do_csum) {
            // c = sum of alpha_{t-1} (identical to old partsA sum; every lane
            // computes the same value -> rc/logZ stay wave-uniform).
            float c = hsum4(cs);
            rc = __builtin_amdgcn_rcpf(c);
            logZ += __logf(c);
        }
        f32x4 s = (acA + acB) + (acC + acD);
        float a = hsum4(s) * ehv;
        if (role == 0) a *= rc;
        Ab[wb][j] = a;
        aout = a;
        barrier_lds_only();
    };

    // ---- group 0: t=0 init + steps 1..3 ----
    {
        float a0 = __expf(startT[j]) * eh[0][0];
        Ab[0][j] = a0;
        aout = a0;
        barrier_lds_only();
        STEP(1, 1, eh[0][1]);
#pragma unroll
        for (int k = 0; k < 4; ++k) eh[1][k] = __expf(emv[k]);   // group 1
        STEP(2, 2, eh[0][2]);
#pragma unroll
        for (int k = 0; k < 4; ++k) emv[k] = emb[(size_t)(8 + k) * CRF_T]; // group 2
        STEP(3, 3, eh[0][3]);
    }

    // ---- groups 1..255 ----
#pragma unroll 1
    for (int g = 1; g < 256; ++g) {
        const int t0 = 4 * g;
        const int cur = g & 1, nxt = cur ^ 1;
        STEP(t0 + 0, 0, eh[cur][0]);
        STEP(t0 + 1, 1, eh[cur][1]);
        if (g <= 254) {
#pragma unroll
            for (int k = 0; k < 4; ++k) eh[nxt][k] = __expf(emv[k]);  // group g+1
        }
        STEP(t0 + 2, 2, eh[cur][2]);
        if (g <= 253) {
#pragma unroll
            for (int k = 0; k < 4; ++k)
                emv[k] = emb[(size_t)(t0 + 8 + k) * CRF_T];  // group g+2
        }
        STEP(t0 + 3, 3, eh[cur][3]);
    }

    // ---- finale: alpha_1023 is in aout (per lane); logZ uniform ----
    float v = (__logf(aout) + logZ) * mlast + endT[j];
    float mx = v;
#pragma unroll
    for (int d = 1; d < 64; d <<= 1) mx = fmaxf(mx, __shfl_xor(mx, d));
    if ((j & 63) == 0) red[j >> 6] = mx;
    __syncthreads();
    mx = fmaxf(red[0], red[1]);
    float ex = __expf(v - mx);
#pragma unroll
    for (int d = 1; d < 64; d <<= 1) ex += __shfl_xor(ex, d);
    if ((j & 63) == 0) red[2 + (j >> 6)] = ex;
    __syncthreads();
    if (j == 0)
        ws[WS_FWD + b] = mx + __logf(red[2] + red[3]);
}

// ---------------------------------------------------------------------------
// Kernel 3: sum the 2304 ws partials (2048 gold already negated + 256 fwd),
// scale by 1/B. One block; replaces all same-address atomics.
// ---------------------------------------------------------------------------
__global__ __launch_bounds__(256) void crf_reduce_kernel(
    const float* __restrict__ ws, float* __restrict__ out)
{
    const int tid = threadIdx.x;
    float s = 0.f;
#pragma unroll
    for (int k = 0; k < WS_N; k += 256) s += ws[k + tid];   // WS_N = 9*256
#pragma unroll
    for (int d = 1; d < 64; d <<= 1) s += __shfl_xor(s, d);
    __shared__ float r4[4];
    if ((tid & 63) == 0) r4[tid >> 6] = s;
    __syncthreads();
    if (tid == 0)
        out[0] = ((r4[0] + r4[1]) + (r4[2] + r4[3])) * (1.0f / CRF_B);
}

// ---------------------------------------------------------------------------
extern "C" void kernel_launch(void* const* d_in, const int* in_sizes, int n_in,
                              void* d_out, int out_size, void* d_ws, size_t ws_size,
                              hipStream_t stream)
{
    const float* em     = (const float*)d_in[0];
    const int*   tags   = (const int*)d_in[1];
    const float* mask   = (const float*)d_in[2];
    const float* startT = (const float*)d_in[3];
    const float* endT   = (const float*)d_in[4];
    const float* trans  = (const float*)d_in[5];
    float* out = (float*)d_out;
    float* ws  = (float*)d_ws;

    hipLaunchKernelGGL(crf_gold_kernel, dim3(CRF_B * GSPLIT), dim3(256), 0, stream,
                       em, tags, mask, startT, endT, trans, ws);
    hipLaunchKernelGGL(crf_fwd_kernel, dim3(CRF_B), dim3(128), 0, stream,
                       em, mask, startT, endT, trans, ws);
    hipLaunchKernelGGL(crf_reduce_kernel, dim3(1), dim3(256), 0, stream,
                       ws, out);
}